// Round 1
// baseline (688.105 us; speedup 1.0000x reference)
//
#include <hip/hip_runtime.h>
#include <math.h>

// GatedAttention B=32, C=512, T=1024, fp32 in/out.
// Split-bf16 (hi/lo) MFMA implementation:
//   T0: transpose+split x -> xThi/xTlo[b,t,c] (bf16), transpose gv -> gvT[b,t,d] (fp32)
//   W:  split Wq/Wk/Wv -> hi/lo bf16 planes [d][c]
//   G1: qT[d,t] = gq[d,t]*(Wq . xT + bq)      (M=d,N=t,K=c)  -> Qhi/Qlo [d][t]
//       kT[d,t] likewise                                      -> Khi/Klo [d][t]
//       v[t,d]  = gvT[t,d]*(xT . Wv^T + bv)   (M=t,N=d,K=c)  -> Vhi/Vlo [t][d]
//   G2: E[c,d] = SCALE * Q[c,:] . K[d,:]      (K=t=1024), fp32
//   S:  row softmax over d, split -> Ahi/Alo [c][d]
//   G3: out[c,t] = attn[c,:] . V[t,:]^T       (K=d=512), fp32 direct to d_out
// All GEMMs are NT form: A[m][k], B[n][k], both k-contiguous; 3 MFMA passes
// (Ah*Bh + Ah*Bl + Al*Bh) approximate fp32 to ~2^-16 relative.
//
// R1 change: K-loop rewritten as double-buffered 2-phase pipeline (T3-minimum):
// LDS 2x32KB, stage tile t+1 BEFORE computing tile t, ONE __syncthreads per
// K-step (its vmcnt(0) drain lands after ~900cy of MFMA instead of right after
// issue). Unrolled 2 steps/iter so buffer indices are compile-time constants.

#define B_ 32
#define C_ 512
#define T_ 1024
#define TC_ ((size_t)524288)   // T*C == C*T
#define CC_ ((size_t)262144)   // C*C
#define SCALE_ 0.04419417382415922f  // 1/sqrt(512)

typedef short bf16x8 __attribute__((ext_vector_type(8)));
typedef float f32x4 __attribute__((ext_vector_type(4)));

__device__ __forceinline__ unsigned short f2b(float f) {
    unsigned int u = __float_as_uint(f);
    u += 0x7fff + ((u >> 16) & 1);          // round-to-nearest-even
    return (unsigned short)(u >> 16);
}
__device__ __forceinline__ float b2f(unsigned short h) {
    return __uint_as_float(((unsigned int)h) << 16);
}

#define GLDS(gp, lp) __builtin_amdgcn_global_load_lds( \
    (const __attribute__((address_space(1))) unsigned int*)(const void*)(gp), \
    (__attribute__((address_space(3))) unsigned int*)(void*)(lp), 16, 0, 0)

// ---------------- generic split-bf16 NT GEMM ----------------
// C[m][n] = sum_k A[m][k]*B[n][k], 128x128 tile, BK=32, 256 threads (4 waves),
// each wave a 64x64 quadrant as 4x4 grid of 16x16x32 MFMA tiles.
// EP 0: val=gate[m*N+n]*(acc+bias[m]), split-store -> Chi/Clo
// EP 1: val=gate[m*N+n]*(acc+bias[n]), split-store -> Chi/Clo
// EP 2: Cf[m*N+n] = acc*SCALE_
// EP 3: Cf[m*N+n] = acc
template<int M, int N, int K, int EP>
__global__ __launch_bounds__(256, 2) void gemm_nt(
    const unsigned short* __restrict__ Ahi, const unsigned short* __restrict__ Alo, size_t sA,
    const unsigned short* __restrict__ Bhi, const unsigned short* __restrict__ Blo, size_t sB,
    float* __restrict__ Cf, size_t sCf,
    unsigned short* __restrict__ Chi, unsigned short* __restrict__ Clo, size_t sC,
    const float* __restrict__ gate, size_t sG,
    const float* __restrict__ bias)
{
    // double-buffered tiles: 2 x (4 planes x 8KB) = 64KB
    __shared__ __attribute__((aligned(16))) unsigned short sAh[2][128 * 32];
    __shared__ __attribute__((aligned(16))) unsigned short sAl[2][128 * 32];
    __shared__ __attribute__((aligned(16))) unsigned short sBh[2][128 * 32];
    __shared__ __attribute__((aligned(16))) unsigned short sBl[2][128 * 32];

    const int tid  = threadIdx.x;
    const int lane = tid & 63;
    const int wave = tid >> 6;
    const int bz   = blockIdx.z;
    const int m0   = blockIdx.y * 128;
    const int n0   = blockIdx.x * 128;

    const unsigned short* pAh = Ahi + (size_t)bz * sA;
    const unsigned short* pAl = Alo + (size_t)bz * sA;
    const unsigned short* pBh = Bhi + (size_t)bz * sB;
    const unsigned short* pBl = Blo + (size_t)bz * sB;

    // staging: wave stages rows [wave*32, wave*32+32) of both tiles, 2 issues of
    // 16 rows each; lane -> row srow+lane/4, k-chunk (lane&3)*8. LDS dest is
    // wave-uniform base + lane*16 (global_load_lds semantics).
    const int srow = wave * 32;
    const int lr   = lane >> 2;
    const int lk   = (lane & 3) * 8;
    const size_t gA0 = (size_t)(m0 + srow + lr) * K + lk;
    const size_t gA1 = (size_t)(m0 + srow + 16 + lr) * K + lk;
    const size_t gB0 = (size_t)(n0 + srow + lr) * K + lk;
    const size_t gB1 = (size_t)(n0 + srow + 16 + lr) * K + lk;

    // fragment coords
    const int wm = (wave & 1) * 64;
    const int wn = (wave >> 1) * 64;
    const int fr = lane & 15;
    const int fk = (lane >> 4) * 8;

    f32x4 acc[4][4] = {};

#define STAGE(b, koff) do { \
    GLDS(pAh + gA0 + (koff), &sAh[b][srow * 32]); \
    GLDS(pAh + gA1 + (koff), &sAh[b][(srow + 16) * 32]); \
    GLDS(pAl + gA0 + (koff), &sAl[b][srow * 32]); \
    GLDS(pAl + gA1 + (koff), &sAl[b][(srow + 16) * 32]); \
    GLDS(pBh + gB0 + (koff), &sBh[b][srow * 32]); \
    GLDS(pBh + gB1 + (koff), &sBh[b][(srow + 16) * 32]); \
    GLDS(pBl + gB0 + (koff), &sBl[b][srow * 32]); \
    GLDS(pBl + gB1 + (koff), &sBl[b][(srow + 16) * 32]); \
} while (0)

#define COMPUTE(b) do { \
    bf16x8 aH[4], aL[4], bH[4], bL[4]; \
    _Pragma("unroll") \
    for (int i = 0; i < 4; ++i) { \
        int ar = (wm + i * 16 + fr) * 32 + fk; \
        int br = (wn + i * 16 + fr) * 32 + fk; \
        aH[i] = *(const bf16x8*)(const void*)&sAh[b][ar]; \
        aL[i] = *(const bf16x8*)(const void*)&sAl[b][ar]; \
        bH[i] = *(const bf16x8*)(const void*)&sBh[b][br]; \
        bL[i] = *(const bf16x8*)(const void*)&sBl[b][br]; \
    } \
    _Pragma("unroll") \
    for (int mi = 0; mi < 4; ++mi) \
        _Pragma("unroll") \
        for (int ni = 0; ni < 4; ++ni) { \
            acc[mi][ni] = __builtin_amdgcn_mfma_f32_16x16x32_bf16(aL[mi], bH[ni], acc[mi][ni], 0, 0, 0); \
            acc[mi][ni] = __builtin_amdgcn_mfma_f32_16x16x32_bf16(aH[mi], bL[ni], acc[mi][ni], 0, 0, 0); \
            acc[mi][ni] = __builtin_amdgcn_mfma_f32_16x16x32_bf16(aH[mi], bH[ni], acc[mi][ni], 0, 0, 0); \
        } \
} while (0)

    // prologue: fill buffer 0, drain
    STAGE(0, 0);
    __syncthreads();

    // steady state: stage(next buffer) issued BEFORE compute(current); the
    // single __syncthreads per step drains vmcnt AFTER compute has run, so
    // HBM/L2 latency hides under the 48 MFMAs.
    // Buffer-overwrite safety: STAGE(b,...) targets the buffer last READ one
    // step earlier, and every wave passed that step's __syncthreads already.
    for (int k0 = 0; k0 < K; k0 += 64) {
        STAGE(1, k0 + 32);          // k0+32 < K always (K % 64 == 0)
        COMPUTE(0);
        __syncthreads();
        if (k0 + 64 < K) STAGE(0, k0 + 64);
        COMPUTE(1);
        __syncthreads();
    }

#undef STAGE
#undef COMPUTE

    // epilogue: C/D layout col=lane&15 (n), row=(lane>>4)*4+reg (m)
    #pragma unroll
    for (int mi = 0; mi < 4; ++mi) {
        #pragma unroll
        for (int r = 0; r < 4; ++r) {
            int m = m0 + wm + mi * 16 + (lane >> 4) * 4 + r;
            #pragma unroll
            for (int ni = 0; ni < 4; ++ni) {
                int n = n0 + wn + ni * 16 + fr;
                float v = acc[mi][ni][r];
                size_t idx = (size_t)m * N + n;
                if (EP == 0 || EP == 1) {
                    float g = gate[(size_t)bz * sG + idx];
                    float val = g * (v + bias[EP == 0 ? m : n]);
                    unsigned short h = f2b(val);
                    Chi[(size_t)bz * sC + idx] = h;
                    Clo[(size_t)bz * sC + idx] = f2b(val - b2f(h));
                } else if (EP == 2) {
                    Cf[(size_t)bz * sCf + idx] = v * SCALE_;
                } else {
                    Cf[(size_t)bz * sCf + idx] = v;
                }
            }
        }
    }
}

// ---------------- transpose + split ----------------
// job 0: x[b,c,t] fp32 -> xThi/xTlo[bz,t,c] bf16
// job 1: gv[b,d,t] fp32 -> gvT[bz,t,d] fp32
__global__ __launch_bounds__(256) void transpose_split(
    const float* __restrict__ x, const float* __restrict__ gv,
    unsigned short* __restrict__ xThi, unsigned short* __restrict__ xTlo,
    float* __restrict__ gvT, int bc, int b_off)
{
    __shared__ float s[64][65];
    const int z = blockIdx.z;
    const int job = z / bc, bz = z % bc;
    const int t0 = blockIdx.x * 64, c0 = blockIdx.y * 64;
    const float* src = (job ? gv : x) + (size_t)(b_off + bz) * TC_;
    const int col = threadIdx.x & 63, rb = threadIdx.x >> 6;

    #pragma unroll
    for (int i = 0; i < 64; i += 4)
        s[i + rb][col] = src[(size_t)(c0 + i + rb) * T_ + t0 + col];
    __syncthreads();

    const size_t ob = (size_t)bz * TC_;
    #pragma unroll
    for (int i = 0; i < 64; i += 4) {
        int tr = i + rb;
        float v = s[col][tr];
        size_t o = ob + (size_t)(t0 + tr) * C_ + c0 + col;
        if (job == 0) {
            unsigned short h = f2b(v);
            xThi[o] = h;
            xTlo[o] = f2b(v - b2f(h));
        } else {
            gvT[o] = v;
        }
    }
}

__global__ __launch_bounds__(256) void split_mat(
    const float* __restrict__ W, unsigned short* __restrict__ hi,
    unsigned short* __restrict__ lo, int n)
{
    int i = blockIdx.x * 256 + threadIdx.x;
    if (i < n) {
        float v = W[i];
        unsigned short h = f2b(v);
        hi[i] = h;
        lo[i] = f2b(v - b2f(h));
    }
}

// row softmax over 512, then split-store attn to bf16 hi/lo
__global__ __launch_bounds__(256) void softmax_split(
    const float* __restrict__ E, unsigned short* __restrict__ Ahi,
    unsigned short* __restrict__ Alo)
{
    const int row = blockIdx.x;
    const float* p = E + (size_t)row * C_;
    const int tid = threadIdx.x;

    float v0 = p[tid], v1 = p[tid + 256];
    float m = fmaxf(v0, v1);
    #pragma unroll
    for (int off = 32; off > 0; off >>= 1)
        m = fmaxf(m, __shfl_down(m, off, 64));

    __shared__ float sm[4];
    if ((tid & 63) == 0) sm[tid >> 6] = m;
    __syncthreads();
    float M = fmaxf(fmaxf(sm[0], sm[1]), fmaxf(sm[2], sm[3]));

    float e0 = expf(v0 - M), e1 = expf(v1 - M);
    float s = e0 + e1;
    #pragma unroll
    for (int off = 32; off > 0; off >>= 1)
        s += __shfl_down(s, off, 64);

    __shared__ float ss[4];
    if ((tid & 63) == 0) ss[tid >> 6] = s;
    __syncthreads();
    float inv = 1.0f / (ss[0] + ss[1] + ss[2] + ss[3]);

    float a0 = e0 * inv, a1 = e1 * inv;
    size_t o = (size_t)row * C_ + tid;
    unsigned short h0 = f2b(a0);
    Ahi[o] = h0;  Alo[o] = f2b(a0 - b2f(h0));
    unsigned short h1 = f2b(a1);
    Ahi[o + 256] = h1;  Alo[o + 256] = f2b(a1 - b2f(h1));
}

extern "C" void kernel_launch(void* const* d_in, const int* in_sizes, int n_in,
                              void* d_out, int out_size, void* d_ws, size_t ws_size,
                              hipStream_t stream) {
    const float* x  = (const float*)d_in[0];
    const float* gq = (const float*)d_in[1];
    const float* gk = (const float*)d_in[2];
    const float* gv = (const float*)d_in[3];
    const float* Wq = (const float*)d_in[4];
    const float* bq = (const float*)d_in[5];
    const float* Wk = (const float*)d_in[6];
    const float* bk = (const float*)d_in[7];
    const float* Wv = (const float*)d_in[8];
    const float* bv = (const float*)d_in[9];
    float* out = (float*)d_out;

    // Workspace: W planes (batch-independent) + per-batch region.
    // per batch: xT hi/lo 2*TC*2 + gvT TC*4 + QKV hi/lo 6*TC*2 + E CC*4 + attn 2*CC*2
    const size_t wBytes = 6 * CC_ * 2;                                  // 3 MB
    const size_t perBatch = 2 * TC_ * 2 + TC_ * 4 + 6 * TC_ * 2
                          + CC_ * 4 + 2 * CC_ * 2;                       // 12 MB
    int bc = 1;
    for (int cand = B_; cand >= 1; cand >>= 1)
        if (wBytes + (size_t)cand * perBatch <= ws_size) { bc = cand; break; }

    char* p = (char*)d_ws;
    auto take = [&](size_t bytes) { char* r = p; p += bytes; return r; };
    unsigned short* Wqh = (unsigned short*)take(CC_ * 2);
    unsigned short* Wql = (unsigned short*)take(CC_ * 2);
    unsigned short* Wkh = (unsigned short*)take(CC_ * 2);
    unsigned short* Wkl = (unsigned short*)take(CC_ * 2);
    unsigned short* Wvh = (unsigned short*)take(CC_ * 2);
    unsigned short* Wvl = (unsigned short*)take(CC_ * 2);
    unsigned short* xThi = (unsigned short*)take((size_t)bc * TC_ * 2);
    unsigned short* xTlo = (unsigned short*)take((size_t)bc * TC_ * 2);
    float*          gvT  = (float*)take((size_t)bc * TC_ * 4);
    unsigned short* Qh = (unsigned short*)take((size_t)bc * TC_ * 2);
    unsigned short* Ql = (unsigned short*)take((size_t)bc * TC_ * 2);
    unsigned short* Kh = (unsigned short*)take((size_t)bc * TC_ * 2);
    unsigned short* Kl = (unsigned short*)take((size_t)bc * TC_ * 2);
    unsigned short* Vh = (unsigned short*)take((size_t)bc * TC_ * 2);
    unsigned short* Vl = (unsigned short*)take((size_t)bc * TC_ * 2);
    float*          E  = (float*)take((size_t)bc * CC_ * 4);
    unsigned short* Ah = (unsigned short*)take((size_t)bc * CC_ * 2);
    unsigned short* Al = (unsigned short*)take((size_t)bc * CC_ * 2);

    dim3 blk(256);
    split_mat<<<(int)(CC_ / 256), blk, 0, stream>>>(Wq, Wqh, Wql, (int)CC_);
    split_mat<<<(int)(CC_ / 256), blk, 0, stream>>>(Wk, Wkh, Wkl, (int)CC_);
    split_mat<<<(int)(CC_ / 256), blk, 0, stream>>>(Wv, Wvh, Wvl, (int)CC_);

    for (int b_off = 0; b_off < B_; b_off += bc) {
        transpose_split<<<dim3(T_ / 64, C_ / 64, 2 * bc), blk, 0, stream>>>(
            x, gv, xThi, xTlo, gvT, bc, b_off);

        // qT[d,t], kT[d,t]: M=512(d), N=1024(t), K=512(c)
        gemm_nt<512, 1024, 512, 0><<<dim3(8, 4, bc), blk, 0, stream>>>(
            Wqh, Wql, 0, xThi, xTlo, TC_, nullptr, 0, Qh, Ql, TC_,
            gq + (size_t)b_off * TC_, TC_, bq);
        gemm_nt<512, 1024, 512, 0><<<dim3(8, 4, bc), blk, 0, stream>>>(
            Wkh, Wkl, 0, xThi, xTlo, TC_, nullptr, 0, Kh, Kl, TC_,
            gk + (size_t)b_off * TC_, TC_, bk);
        // v[t,d]: M=1024(t), N=512(d), K=512(c); gate gvT local-batch
        gemm_nt<1024, 512, 512, 1><<<dim3(4, 8, bc), blk, 0, stream>>>(
            xThi, xTlo, TC_, Wvh, Wvl, 0, nullptr, 0, Vh, Vl, TC_,
            gvT, TC_, bv);
        // E[c,d]: M=512, N=512, K=1024(t)
        gemm_nt<512, 512, 1024, 2><<<dim3(4, 4, bc), blk, 0, stream>>>(
            Qh, Ql, TC_, Kh, Kl, TC_, E, CC_, nullptr, nullptr, 0, nullptr, 0, nullptr);
        softmax_split<<<dim3(bc * C_), blk, 0, stream>>>(E, Ah, Al);
        // out[c,t]: M=512(c), N=1024(t), K=512(d)
        gemm_nt<512, 1024, 512, 3><<<dim3(8, 4, bc), blk, 0, stream>>>(
            Ah, Al, CC_, Vh, Vl, TC_, out + (size_t)b_off * TC_, TC_,
            nullptr, nullptr, 0, nullptr, 0, nullptr);
    }
}

// Round 2
// 679.651 us; speedup vs baseline: 1.0124x; 1.0124x over previous
//
#include <hip/hip_runtime.h>
#include <math.h>

// GatedAttention B=32, C=512, T=1024, fp32 in/out.
// Split-bf16 (hi/lo) MFMA implementation:
//   T0: transpose+split x -> xThi/xTlo[b,t,c] (bf16), transpose gv -> gvT[b,t,d] (fp32)
//   W:  split Wq/Wk/Wv -> hi/lo bf16 planes [d][c]
//   G1: qT[d,t] = gq[d,t]*(Wq . xT + bq)      (M=d,N=t,K=c)  -> Qhi/Qlo [d][t]
//       kT[d,t] likewise                                      -> Khi/Klo [d][t]
//       v[t,d]  = gvT[t,d]*(xT . Wv^T + bv)   (M=t,N=d,K=c)  -> Vhi/Vlo [t][d]
//   G2: E[c,d] = SCALE * Q[c,:] . K[d,:]      (K=t=1024), fp32, SPLIT-K x2
//   S:  row softmax over d (sums the 2 K-slabs), split -> Ahi/Alo [c][d]
//   G3: out[c,t] = attn[c,:] . V[t,:]^T       (K=d=512), fp32 direct to d_out
// All GEMMs are NT form: A[m][k], B[n][k], both k-contiguous; 3 MFMA passes
// (Ah*Bh + Ah*Bl + Al*Bh) approximate fp32 to ~2^-16 relative.
//
// R2 changes:
//  (a) Double-buffer LDS as SEPARATE __shared__ objects. With one sAh[2][..]
//      array, LLVM cannot disambiguate global_load_lds writes to buf1 from
//      ds_reads of buf0 (runtime offsets, same object) and inserts
//      s_waitcnt vmcnt(0) before the ds_reads -> R1's pipeline degenerated to
//      the serial stage->drain->compute pattern (MfmaUtil unchanged at 18%).
//      Separate objects let the vmcnt drain sit at the barrier, ~930 MFMA
//      cycles after issue.
//  (b) E-gemm split-K (2 halves of t), grid 4x4x(2*bc): 2 blocks/CU instead
//      of 1. softmax sums the two E slabs.

#define B_ 32
#define C_ 512
#define T_ 1024
#define TC_ ((size_t)524288)   // T*C == C*T
#define CC_ ((size_t)262144)   // C*C
#define SCALE_ 0.04419417382415922f  // 1/sqrt(512)

typedef short bf16x8 __attribute__((ext_vector_type(8)));
typedef float f32x4 __attribute__((ext_vector_type(4)));

__device__ __forceinline__ unsigned short f2b(float f) {
    unsigned int u = __float_as_uint(f);
    u += 0x7fff + ((u >> 16) & 1);          // round-to-nearest-even
    return (unsigned short)(u >> 16);
}
__device__ __forceinline__ float b2f(unsigned short h) {
    return __uint_as_float(((unsigned int)h) << 16);
}

#define GLDS(gp, lp) __builtin_amdgcn_global_load_lds( \
    (const __attribute__((address_space(1))) unsigned int*)(const void*)(gp), \
    (__attribute__((address_space(3))) unsigned int*)(void*)(lp), 16, 0, 0)

// ---------------- generic split-bf16 NT GEMM ----------------
// C[m][n] = sum_k A[m][k]*B[n][k], 128x128 tile, BK=32, 256 threads (4 waves),
// each wave a 64x64 quadrant as 4x4 grid of 16x16x32 MFMA tiles.
// LD = row stride (elements) of A and B; K = k-extent THIS BLOCK loops over.
// EP 0: val=gate[m*N+n]*(acc+bias[m]), split-store -> Chi/Clo
// EP 1: val=gate[m*N+n]*(acc+bias[n]), split-store -> Chi/Clo
// EP 2: split-K: blockIdx.z = bz*2 + khalf; k-offset khalf*K;
//       Cf[blockIdx.z*sCf + m*N+n] = acc*SCALE_
// EP 3: Cf[m*N+n] = acc
template<int M, int N, int K, int LD, int EP>
__global__ __launch_bounds__(256, 2) void gemm_nt(
    const unsigned short* __restrict__ Ahi, const unsigned short* __restrict__ Alo, size_t sA,
    const unsigned short* __restrict__ Bhi, const unsigned short* __restrict__ Blo, size_t sB,
    float* __restrict__ Cf, size_t sCf,
    unsigned short* __restrict__ Chi, unsigned short* __restrict__ Clo, size_t sC,
    const float* __restrict__ gate, size_t sG,
    const float* __restrict__ bias)
{
    // double-buffered tiles as 8 DISTINCT LDS objects (4 planes x 2 bufs),
    // 8 KB each, 64 KB total -> alias analysis can separate buf0 reads from
    // buf1 global_load_lds writes.
    __shared__ __attribute__((aligned(16))) unsigned short sAh0[128 * 32];
    __shared__ __attribute__((aligned(16))) unsigned short sAl0[128 * 32];
    __shared__ __attribute__((aligned(16))) unsigned short sBh0[128 * 32];
    __shared__ __attribute__((aligned(16))) unsigned short sBl0[128 * 32];
    __shared__ __attribute__((aligned(16))) unsigned short sAh1[128 * 32];
    __shared__ __attribute__((aligned(16))) unsigned short sAl1[128 * 32];
    __shared__ __attribute__((aligned(16))) unsigned short sBh1[128 * 32];
    __shared__ __attribute__((aligned(16))) unsigned short sBl1[128 * 32];

    const int tid  = threadIdx.x;
    const int lane = tid & 63;
    const int wave = tid >> 6;
    const int bz   = (EP == 2) ? (blockIdx.z >> 1) : blockIdx.z;
    const size_t kbase = (EP == 2) ? (size_t)(blockIdx.z & 1) * K : 0;
    const int m0   = blockIdx.y * 128;
    const int n0   = blockIdx.x * 128;

    const unsigned short* pAh = Ahi + (size_t)bz * sA;
    const unsigned short* pAl = Alo + (size_t)bz * sA;
    const unsigned short* pBh = Bhi + (size_t)bz * sB;
    const unsigned short* pBl = Blo + (size_t)bz * sB;

    // staging: wave stages rows [wave*32, wave*32+32) of both tiles, 2 issues of
    // 16 rows each; lane -> row srow+lane/4, k-chunk (lane&3)*8. LDS dest is
    // wave-uniform base + lane*16 (global_load_lds semantics).
    const int srow = wave * 32;
    const int lr   = lane >> 2;
    const int lk   = (lane & 3) * 8;
    const size_t gA0 = (size_t)(m0 + srow + lr) * LD + lk + kbase;
    const size_t gA1 = (size_t)(m0 + srow + 16 + lr) * LD + lk + kbase;
    const size_t gB0 = (size_t)(n0 + srow + lr) * LD + lk + kbase;
    const size_t gB1 = (size_t)(n0 + srow + 16 + lr) * LD + lk + kbase;

    // fragment coords
    const int wm = (wave & 1) * 64;
    const int wn = (wave >> 1) * 64;
    const int fr = lane & 15;
    const int fk = (lane >> 4) * 8;

    f32x4 acc[4][4] = {};

#define STAGE(AH, AL, BH, BL, koff) do { \
    GLDS(pAh + gA0 + (koff), &AH[srow * 32]); \
    GLDS(pAh + gA1 + (koff), &AH[(srow + 16) * 32]); \
    GLDS(pAl + gA0 + (koff), &AL[srow * 32]); \
    GLDS(pAl + gA1 + (koff), &AL[(srow + 16) * 32]); \
    GLDS(pBh + gB0 + (koff), &BH[srow * 32]); \
    GLDS(pBh + gB1 + (koff), &BH[(srow + 16) * 32]); \
    GLDS(pBl + gB0 + (koff), &BL[srow * 32]); \
    GLDS(pBl + gB1 + (koff), &BL[(srow + 16) * 32]); \
} while (0)

#define COMPUTE(AH, AL, BH, BL) do { \
    bf16x8 aH[4], aL[4], bH[4], bL[4]; \
    _Pragma("unroll") \
    for (int i = 0; i < 4; ++i) { \
        int ar = (wm + i * 16 + fr) * 32 + fk; \
        int br = (wn + i * 16 + fr) * 32 + fk; \
        aH[i] = *(const bf16x8*)(const void*)&AH[ar]; \
        aL[i] = *(const bf16x8*)(const void*)&AL[ar]; \
        bH[i] = *(const bf16x8*)(const void*)&BH[br]; \
        bL[i] = *(const bf16x8*)(const void*)&BL[br]; \
    } \
    _Pragma("unroll") \
    for (int mi = 0; mi < 4; ++mi) \
        _Pragma("unroll") \
        for (int ni = 0; ni < 4; ++ni) { \
            acc[mi][ni] = __builtin_amdgcn_mfma_f32_16x16x32_bf16(aL[mi], bH[ni], acc[mi][ni], 0, 0, 0); \
            acc[mi][ni] = __builtin_amdgcn_mfma_f32_16x16x32_bf16(aH[mi], bL[ni], acc[mi][ni], 0, 0, 0); \
            acc[mi][ni] = __builtin_amdgcn_mfma_f32_16x16x32_bf16(aH[mi], bH[ni], acc[mi][ni], 0, 0, 0); \
        } \
} while (0)

    // prologue: fill buffer 0, drain
    STAGE(sAh0, sAl0, sBh0, sBl0, 0);
    __syncthreads();

    // steady state: stage(next buffer) issued BEFORE compute(current); the
    // single __syncthreads per 32-step drains vmcnt AFTER ~930cy of MFMA.
    // Buffer-overwrite safety: STAGE targets the buffer last READ one step
    // earlier, and every wave passed that step's __syncthreads already.
    for (int k0 = 0; k0 < K; k0 += 64) {
        STAGE(sAh1, sAl1, sBh1, sBl1, k0 + 32);   // k0+32 < K (K % 64 == 0)
        COMPUTE(sAh0, sAl0, sBh0, sBl0);
        __syncthreads();
        if (k0 + 64 < K) STAGE(sAh0, sAl0, sBh0, sBl0, k0 + 64);
        COMPUTE(sAh1, sAl1, sBh1, sBl1);
        __syncthreads();
    }

#undef STAGE
#undef COMPUTE

    // epilogue: C/D layout col=lane&15 (n), row=(lane>>4)*4+reg (m)
    #pragma unroll
    for (int mi = 0; mi < 4; ++mi) {
        #pragma unroll
        for (int r = 0; r < 4; ++r) {
            int m = m0 + wm + mi * 16 + (lane >> 4) * 4 + r;
            #pragma unroll
            for (int ni = 0; ni < 4; ++ni) {
                int n = n0 + wn + ni * 16 + fr;
                float v = acc[mi][ni][r];
                size_t idx = (size_t)m * N + n;
                if (EP == 0 || EP == 1) {
                    float g = gate[(size_t)bz * sG + idx];
                    float val = g * (v + bias[EP == 0 ? m : n]);
                    unsigned short h = f2b(val);
                    Chi[(size_t)bz * sC + idx] = h;
                    Clo[(size_t)bz * sC + idx] = f2b(val - b2f(h));
                } else if (EP == 2) {
                    Cf[(size_t)blockIdx.z * sCf + idx] = v * SCALE_;
                } else {
                    Cf[(size_t)bz * sCf + idx] = v;
                }
            }
        }
    }
}

// ---------------- transpose + split ----------------
// job 0: x[b,c,t] fp32 -> xThi/xTlo[bz,t,c] bf16
// job 1: gv[b,d,t] fp32 -> gvT[bz,t,d] fp32
__global__ __launch_bounds__(256) void transpose_split(
    const float* __restrict__ x, const float* __restrict__ gv,
    unsigned short* __restrict__ xThi, unsigned short* __restrict__ xTlo,
    float* __restrict__ gvT, int bc, int b_off)
{
    __shared__ float s[64][65];
    const int z = blockIdx.z;
    const int job = z / bc, bz = z % bc;
    const int t0 = blockIdx.x * 64, c0 = blockIdx.y * 64;
    const float* src = (job ? gv : x) + (size_t)(b_off + bz) * TC_;
    const int col = threadIdx.x & 63, rb = threadIdx.x >> 6;

    #pragma unroll
    for (int i = 0; i < 64; i += 4)
        s[i + rb][col] = src[(size_t)(c0 + i + rb) * T_ + t0 + col];
    __syncthreads();

    const size_t ob = (size_t)bz * TC_;
    #pragma unroll
    for (int i = 0; i < 64; i += 4) {
        int tr = i + rb;
        float v = s[col][tr];
        size_t o = ob + (size_t)(t0 + tr) * C_ + c0 + col;
        if (job == 0) {
            unsigned short h = f2b(v);
            xThi[o] = h;
            xTlo[o] = f2b(v - b2f(h));
        } else {
            gvT[o] = v;
        }
    }
}

__global__ __launch_bounds__(256) void split_mat(
    const float* __restrict__ W, unsigned short* __restrict__ hi,
    unsigned short* __restrict__ lo, int n)
{
    int i = blockIdx.x * 256 + threadIdx.x;
    if (i < n) {
        float v = W[i];
        unsigned short h = f2b(v);
        hi[i] = h;
        lo[i] = f2b(v - b2f(h));
    }
}

// row softmax over 512 (summing the 2 split-K E slabs), then split-store attn
// to bf16 hi/lo. E layout: slab (bz*2+kh) of CC_ floats each.
__global__ __launch_bounds__(256) void softmax_split(
    const float* __restrict__ E, unsigned short* __restrict__ Ahi,
    unsigned short* __restrict__ Alo)
{
    const int row = blockIdx.x;
    const int bz = row >> 9;           // row / C_
    const int c  = row & (C_ - 1);
    const float* p0 = E + (size_t)(2 * bz) * CC_ + (size_t)c * C_;
    const int tid = threadIdx.x;

    float v0 = p0[tid] + p0[CC_ + tid];
    float v1 = p0[tid + 256] + p0[CC_ + tid + 256];
    float m = fmaxf(v0, v1);
    #pragma unroll
    for (int off = 32; off > 0; off >>= 1)
        m = fmaxf(m, __shfl_down(m, off, 64));

    __shared__ float sm[4];
    if ((tid & 63) == 0) sm[tid >> 6] = m;
    __syncthreads();
    float M = fmaxf(fmaxf(sm[0], sm[1]), fmaxf(sm[2], sm[3]));

    float e0 = expf(v0 - M), e1 = expf(v1 - M);
    float s = e0 + e1;
    #pragma unroll
    for (int off = 32; off > 0; off >>= 1)
        s += __shfl_down(s, off, 64);

    __shared__ float ss[4];
    if ((tid & 63) == 0) ss[tid >> 6] = s;
    __syncthreads();
    float inv = 1.0f / (ss[0] + ss[1] + ss[2] + ss[3]);

    float a0 = e0 * inv, a1 = e1 * inv;
    size_t o = (size_t)row * C_ + tid;
    unsigned short h0 = f2b(a0);
    Ahi[o] = h0;  Alo[o] = f2b(a0 - b2f(h0));
    unsigned short h1 = f2b(a1);
    Ahi[o + 256] = h1;  Alo[o + 256] = f2b(a1 - b2f(h1));
}

extern "C" void kernel_launch(void* const* d_in, const int* in_sizes, int n_in,
                              void* d_out, int out_size, void* d_ws, size_t ws_size,
                              hipStream_t stream) {
    const float* x  = (const float*)d_in[0];
    const float* gq = (const float*)d_in[1];
    const float* gk = (const float*)d_in[2];
    const float* gv = (const float*)d_in[3];
    const float* Wq = (const float*)d_in[4];
    const float* bq = (const float*)d_in[5];
    const float* Wk = (const float*)d_in[6];
    const float* bk = (const float*)d_in[7];
    const float* Wv = (const float*)d_in[8];
    const float* bv = (const float*)d_in[9];
    float* out = (float*)d_out;

    // Workspace: W planes (batch-independent) + per-batch region.
    // per batch: xT hi/lo 2*TC*2 + gvT TC*4 + QKV hi/lo 6*TC*2
    //            + E (2 split-K slabs) 2*CC*4 + attn 2*CC*2
    const size_t wBytes = 6 * CC_ * 2;                                  // 3 MB
    const size_t perBatch = 2 * TC_ * 2 + TC_ * 4 + 6 * TC_ * 2
                          + 2 * CC_ * 4 + 2 * CC_ * 2;                   // 13 MB
    int bc = 1;
    for (int cand = B_; cand >= 1; cand >>= 1)
        if (wBytes + (size_t)cand * perBatch <= ws_size) { bc = cand; break; }

    char* p = (char*)d_ws;
    auto take = [&](size_t bytes) { char* r = p; p += bytes; return r; };
    unsigned short* Wqh = (unsigned short*)take(CC_ * 2);
    unsigned short* Wql = (unsigned short*)take(CC_ * 2);
    unsigned short* Wkh = (unsigned short*)take(CC_ * 2);
    unsigned short* Wkl = (unsigned short*)take(CC_ * 2);
    unsigned short* Wvh = (unsigned short*)take(CC_ * 2);
    unsigned short* Wvl = (unsigned short*)take(CC_ * 2);
    unsigned short* xThi = (unsigned short*)take((size_t)bc * TC_ * 2);
    unsigned short* xTlo = (unsigned short*)take((size_t)bc * TC_ * 2);
    float*          gvT  = (float*)take((size_t)bc * TC_ * 4);
    unsigned short* Qh = (unsigned short*)take((size_t)bc * TC_ * 2);
    unsigned short* Ql = (unsigned short*)take((size_t)bc * TC_ * 2);
    unsigned short* Kh = (unsigned short*)take((size_t)bc * TC_ * 2);
    unsigned short* Kl = (unsigned short*)take((size_t)bc * TC_ * 2);
    unsigned short* Vh = (unsigned short*)take((size_t)bc * TC_ * 2);
    unsigned short* Vl = (unsigned short*)take((size_t)bc * TC_ * 2);
    float*          E  = (float*)take((size_t)bc * 2 * CC_ * 4);
    unsigned short* Ah = (unsigned short*)take((size_t)bc * CC_ * 2);
    unsigned short* Al = (unsigned short*)take((size_t)bc * CC_ * 2);

    dim3 blk(256);
    split_mat<<<(int)(CC_ / 256), blk, 0, stream>>>(Wq, Wqh, Wql, (int)CC_);
    split_mat<<<(int)(CC_ / 256), blk, 0, stream>>>(Wk, Wkh, Wkl, (int)CC_);
    split_mat<<<(int)(CC_ / 256), blk, 0, stream>>>(Wv, Wvh, Wvl, (int)CC_);

    for (int b_off = 0; b_off < B_; b_off += bc) {
        transpose_split<<<dim3(T_ / 64, C_ / 64, 2 * bc), blk, 0, stream>>>(
            x, gv, xThi, xTlo, gvT, bc, b_off);

        // qT[d,t], kT[d,t]: M=512(d), N=1024(t), K=512(c)
        gemm_nt<512, 1024, 512, 512, 0><<<dim3(8, 4, bc), blk, 0, stream>>>(
            Wqh, Wql, 0, xThi, xTlo, TC_, nullptr, 0, Qh, Ql, TC_,
            gq + (size_t)b_off * TC_, TC_, bq);
        gemm_nt<512, 1024, 512, 512, 0><<<dim3(8, 4, bc), blk, 0, stream>>>(
            Wkh, Wkl, 0, xThi, xTlo, TC_, nullptr, 0, Kh, Kl, TC_,
            gk + (size_t)b_off * TC_, TC_, bk);
        // v[t,d]: M=1024(t), N=512(d), K=512(c); gate gvT local-batch
        gemm_nt<1024, 512, 512, 512, 1><<<dim3(4, 8, bc), blk, 0, stream>>>(
            xThi, xTlo, TC_, Wvh, Wvl, 0, nullptr, 0, Vh, Vl, TC_,
            gvT, TC_, bv);
        // E[c,d]: M=512, N=512, K split 2x512 over t (LD=1024)
        gemm_nt<512, 512, 512, 1024, 2><<<dim3(4, 4, 2 * bc), blk, 0, stream>>>(
            Qh, Ql, TC_, Kh, Kl, TC_, E, CC_, nullptr, nullptr, 0, nullptr, 0, nullptr);
        softmax_split<<<dim3(bc * C_), blk, 0, stream>>>(E, Ah, Al);
        // out[c,t]: M=512(c), N=1024(t), K=512(d)
        gemm_nt<512, 1024, 512, 512, 3><<<dim3(8, 4, bc), blk, 0, stream>>>(
            Ah, Al, CC_, Vh, Vl, TC_, out + (size_t)b_off * TC_, TC_,
            nullptr, nullptr, 0, nullptr, 0, nullptr);
    }
}

// Round 3
// 623.889 us; speedup vs baseline: 1.1029x; 1.0894x over previous
//
#include <hip/hip_runtime.h>
#include <math.h>

// GatedAttention B=32, C=512, T=1024, fp32 in/out.
// Split-bf16 (hi/lo) MFMA implementation:
//   T0: transpose+split x -> xThi/xTlo[b,t,c] (bf16), transpose gv -> gvT[b,t,d] (fp32)
//   W:  split Wq/Wk/Wv -> hi/lo bf16 planes [d][c]
//   G1: qT[d,t] = gq[d,t]*(Wq . xT + bq)      (M=d,N=t,K=c)  -> Qhi/Qlo [d][t]
//       kT[d,t] likewise                                      -> Khi/Klo [d][t]
//       v[t,d]  = gvT[t,d]*(xT . Wv^T + bv)   (M=t,N=d,K=c)  -> Vhi/Vlo [t][d]
//   G2: E[c,d] = SCALE * Q[c,:] . K[d,:]      (K=t=1024), fp32, SPLIT-K x2
//   S:  row softmax over d (sums the 2 K-slabs), split -> Ahi/Alo [c][d]
//   G3: out[c,t] = attn[c,:] . V[t,:]^T       (K=d=512), fp32 direct to d_out
// All GEMMs are NT form: A[m][k], B[n][k], both k-contiguous; 3 MFMA passes
// (Ah*Bh + Ah*Bl + Al*Bh) approximate fp32 to ~2^-16 relative.
//
// R3 change: T1 XCD-locality remap. R0-R2 all show identical gemm counters
// (~51us, MfmaUtil 18%, every pipe <20% busy) regardless of pipelining or
// occupancy -> staging-bandwidth wall, not latency. Default block->XCD
// round-robin sprays each batch's operand panels across all 8 XCDs, so
// staging is served by remote L3 instead of local L2. Now every gemm
// launches a 1-D grid and decodes block->(tile,batch) such that all blocks
// of one batch land on one XCD (linear wg id i -> XCD i%8): per-XCD L2
// holds that batch's panels (per-K-step working set ~384KB << 4MiB) and
// staging runs at local-L2 bandwidth.

#define B_ 32
#define C_ 512
#define T_ 1024
#define TC_ ((size_t)524288)   // T*C == C*T
#define CC_ ((size_t)262144)   // C*C
#define SCALE_ 0.04419417382415922f  // 1/sqrt(512)

typedef short bf16x8 __attribute__((ext_vector_type(8)));
typedef float f32x4 __attribute__((ext_vector_type(4)));

__device__ __forceinline__ unsigned short f2b(float f) {
    unsigned int u = __float_as_uint(f);
    u += 0x7fff + ((u >> 16) & 1);          // round-to-nearest-even
    return (unsigned short)(u >> 16);
}
__device__ __forceinline__ float b2f(unsigned short h) {
    return __uint_as_float(((unsigned int)h) << 16);
}

#define GLDS(gp, lp) __builtin_amdgcn_global_load_lds( \
    (const __attribute__((address_space(1))) unsigned int*)(const void*)(gp), \
    (__attribute__((address_space(3))) unsigned int*)(void*)(lp), 16, 0, 0)

// ---------------- generic split-bf16 NT GEMM ----------------
// C[m][n] = sum_k A[m][k]*B[n][k], 128x128 tile, BK=32, 256 threads (4 waves),
// each wave a 64x64 quadrant as 4x4 grid of 16x16x32 MFMA tiles.
// LD = row stride (elements) of A and B; K = k-extent THIS BLOCK loops over.
// GX = tiles in n direction (tile decode); tiles in m = M/128.
// 1-D grid, XCD-locality decode (see header comment).
// EP 0: val=gate[m*N+n]*(acc+bias[m]), split-store -> Chi/Clo
// EP 1: val=gate[m*N+n]*(acc+bias[n]), split-store -> Chi/Clo
// EP 2: split-K: z = bz*2 + khalf; k-offset khalf*K;
//       Cf[z*sCf + m*N+n] = acc*SCALE_
// EP 3: Cf[m*N+n] = acc
template<int M, int N, int K, int LD, int GX, int EP>
__global__ __launch_bounds__(256, 2) void gemm_nt(
    const unsigned short* __restrict__ Ahi, const unsigned short* __restrict__ Alo, size_t sA,
    const unsigned short* __restrict__ Bhi, const unsigned short* __restrict__ Blo, size_t sB,
    float* __restrict__ Cf, size_t sCf,
    unsigned short* __restrict__ Chi, unsigned short* __restrict__ Clo, size_t sC,
    const float* __restrict__ gate, size_t sG,
    const float* __restrict__ bias,
    int nbatch)   // bc (number of batches in this launch)
{
    // double-buffered tiles as 8 DISTINCT LDS objects (4 planes x 2 bufs)
    __shared__ __attribute__((aligned(16))) unsigned short sAh0[128 * 32];
    __shared__ __attribute__((aligned(16))) unsigned short sAl0[128 * 32];
    __shared__ __attribute__((aligned(16))) unsigned short sBh0[128 * 32];
    __shared__ __attribute__((aligned(16))) unsigned short sBl0[128 * 32];
    __shared__ __attribute__((aligned(16))) unsigned short sAh1[128 * 32];
    __shared__ __attribute__((aligned(16))) unsigned short sAl1[128 * 32];
    __shared__ __attribute__((aligned(16))) unsigned short sBh1[128 * 32];
    __shared__ __attribute__((aligned(16))) unsigned short sBl1[128 * 32];

    constexpr int NXY = GX * (M / 128);   // tiles per (batch, khalf)

    const int tid  = threadIdx.x;
    const int lane = tid & 63;
    const int wave = tid >> 6;

    // ---- XCD-locality decode: all blocks of one batch -> one XCD ----
    const int l = blockIdx.x;
    int tile, z;   // z = batch (EP!=2) or bz*2+khalf (EP==2)
    if (EP == 2) {
        if (nbatch >= 8) {
            const int g = nbatch >> 3;        // 1 or 2
            const int r = l >> 3;
            const int q = r % (2 * g);        // encodes (bz_hi, khalf)
            tile = r / (2 * g);
            const int bzv = (l & 7) + ((q % g) << 3);
            z = bzv * 2 + (q / g);
        } else { tile = l % NXY; z = l / NXY; }
    } else {
        if (nbatch >= 8) {
            const int g = nbatch >> 3;        // 1 or 2
            const int r = l >> 3;
            z = (l & 7) + ((r % g) << 3);
            tile = r / g;
        } else { tile = l % NXY; z = l / NXY; }
    }
    const int bz   = (EP == 2) ? (z >> 1) : z;
    const size_t kbase = (EP == 2) ? (size_t)(z & 1) * K : 0;
    const int m0   = (tile / GX) * 128;
    const int n0   = (tile % GX) * 128;

    const unsigned short* pAh = Ahi + (size_t)bz * sA;
    const unsigned short* pAl = Alo + (size_t)bz * sA;
    const unsigned short* pBh = Bhi + (size_t)bz * sB;
    const unsigned short* pBl = Blo + (size_t)bz * sB;

    // staging: wave stages rows [wave*32, wave*32+32) of both tiles, 2 issues of
    // 16 rows each; lane -> row srow+lane/4, k-chunk (lane&3)*8. LDS dest is
    // wave-uniform base + lane*16 (global_load_lds semantics).
    const int srow = wave * 32;
    const int lr   = lane >> 2;
    const int lk   = (lane & 3) * 8;
    const size_t gA0 = (size_t)(m0 + srow + lr) * LD + lk + kbase;
    const size_t gA1 = (size_t)(m0 + srow + 16 + lr) * LD + lk + kbase;
    const size_t gB0 = (size_t)(n0 + srow + lr) * LD + lk + kbase;
    const size_t gB1 = (size_t)(n0 + srow + 16 + lr) * LD + lk + kbase;

    // fragment coords
    const int wm = (wave & 1) * 64;
    const int wn = (wave >> 1) * 64;
    const int fr = lane & 15;
    const int fk = (lane >> 4) * 8;

    f32x4 acc[4][4] = {};

#define STAGE(AH, AL, BH, BL, koff) do { \
    GLDS(pAh + gA0 + (koff), &AH[srow * 32]); \
    GLDS(pAh + gA1 + (koff), &AH[(srow + 16) * 32]); \
    GLDS(pAl + gA0 + (koff), &AL[srow * 32]); \
    GLDS(pAl + gA1 + (koff), &AL[(srow + 16) * 32]); \
    GLDS(pBh + gB0 + (koff), &BH[srow * 32]); \
    GLDS(pBh + gB1 + (koff), &BH[(srow + 16) * 32]); \
    GLDS(pBl + gB0 + (koff), &BL[srow * 32]); \
    GLDS(pBl + gB1 + (koff), &BL[(srow + 16) * 32]); \
} while (0)

#define COMPUTE(AH, AL, BH, BL) do { \
    bf16x8 aH[4], aL[4], bH[4], bL[4]; \
    _Pragma("unroll") \
    for (int i = 0; i < 4; ++i) { \
        int ar = (wm + i * 16 + fr) * 32 + fk; \
        int br = (wn + i * 16 + fr) * 32 + fk; \
        aH[i] = *(const bf16x8*)(const void*)&AH[ar]; \
        aL[i] = *(const bf16x8*)(const void*)&AL[ar]; \
        bH[i] = *(const bf16x8*)(const void*)&BH[br]; \
        bL[i] = *(const bf16x8*)(const void*)&BL[br]; \
    } \
    _Pragma("unroll") \
    for (int mi = 0; mi < 4; ++mi) \
        _Pragma("unroll") \
        for (int ni = 0; ni < 4; ++ni) { \
            acc[mi][ni] = __builtin_amdgcn_mfma_f32_16x16x32_bf16(aL[mi], bH[ni], acc[mi][ni], 0, 0, 0); \
            acc[mi][ni] = __builtin_amdgcn_mfma_f32_16x16x32_bf16(aH[mi], bL[ni], acc[mi][ni], 0, 0, 0); \
            acc[mi][ni] = __builtin_amdgcn_mfma_f32_16x16x32_bf16(aH[mi], bH[ni], acc[mi][ni], 0, 0, 0); \
        } \
} while (0)

    // prologue: fill buffer 0, drain
    STAGE(sAh0, sAl0, sBh0, sBl0, 0);
    __syncthreads();

    for (int k0 = 0; k0 < K; k0 += 64) {
        STAGE(sAh1, sAl1, sBh1, sBl1, k0 + 32);   // k0+32 < K (K % 64 == 0)
        COMPUTE(sAh0, sAl0, sBh0, sBl0);
        __syncthreads();
        if (k0 + 64 < K) STAGE(sAh0, sAl0, sBh0, sBl0, k0 + 64);
        COMPUTE(sAh1, sAl1, sBh1, sBl1);
        __syncthreads();
    }

#undef STAGE
#undef COMPUTE

    // epilogue: C/D layout col=lane&15 (n), row=(lane>>4)*4+reg (m)
    #pragma unroll
    for (int mi = 0; mi < 4; ++mi) {
        #pragma unroll
        for (int r = 0; r < 4; ++r) {
            int m = m0 + wm + mi * 16 + (lane >> 4) * 4 + r;
            #pragma unroll
            for (int ni = 0; ni < 4; ++ni) {
                int n = n0 + wn + ni * 16 + fr;
                float v = acc[mi][ni][r];
                size_t idx = (size_t)m * N + n;
                if (EP == 0 || EP == 1) {
                    float g = gate[(size_t)bz * sG + idx];
                    float val = g * (v + bias[EP == 0 ? m : n]);
                    unsigned short h = f2b(val);
                    Chi[(size_t)bz * sC + idx] = h;
                    Clo[(size_t)bz * sC + idx] = f2b(val - b2f(h));
                } else if (EP == 2) {
                    Cf[(size_t)z * sCf + idx] = v * SCALE_;
                } else {
                    Cf[(size_t)bz * sCf + idx] = v;
                }
            }
        }
    }
}

// ---------------- transpose + split ----------------
// job 0: x[b,c,t] fp32 -> xThi/xTlo[bz,t,c] bf16
// job 1: gv[b,d,t] fp32 -> gvT[bz,t,d] fp32
__global__ __launch_bounds__(256) void transpose_split(
    const float* __restrict__ x, const float* __restrict__ gv,
    unsigned short* __restrict__ xThi, unsigned short* __restrict__ xTlo,
    float* __restrict__ gvT, int bc, int b_off)
{
    __shared__ float s[64][65];
    const int z = blockIdx.z;
    const int job = z / bc, bz = z % bc;
    const int t0 = blockIdx.x * 64, c0 = blockIdx.y * 64;
    const float* src = (job ? gv : x) + (size_t)(b_off + bz) * TC_;
    const int col = threadIdx.x & 63, rb = threadIdx.x >> 6;

    #pragma unroll
    for (int i = 0; i < 64; i += 4)
        s[i + rb][col] = src[(size_t)(c0 + i + rb) * T_ + t0 + col];
    __syncthreads();

    const size_t ob = (size_t)bz * TC_;
    #pragma unroll
    for (int i = 0; i < 64; i += 4) {
        int tr = i + rb;
        float v = s[col][tr];
        size_t o = ob + (size_t)(t0 + tr) * C_ + c0 + col;
        if (job == 0) {
            unsigned short h = f2b(v);
            xThi[o] = h;
            xTlo[o] = f2b(v - b2f(h));
        } else {
            gvT[o] = v;
        }
    }
}

__global__ __launch_bounds__(256) void split_mat(
    const float* __restrict__ W, unsigned short* __restrict__ hi,
    unsigned short* __restrict__ lo, int n)
{
    int i = blockIdx.x * 256 + threadIdx.x;
    if (i < n) {
        float v = W[i];
        unsigned short h = f2b(v);
        hi[i] = h;
        lo[i] = f2b(v - b2f(h));
    }
}

// row softmax over 512 (summing the 2 split-K E slabs), then split-store attn
// to bf16 hi/lo. E layout: slab (bz*2+kh) of CC_ floats each.
__global__ __launch_bounds__(256) void softmax_split(
    const float* __restrict__ E, unsigned short* __restrict__ Ahi,
    unsigned short* __restrict__ Alo)
{
    const int row = blockIdx.x;
    const int bz = row >> 9;           // row / C_
    const int c  = row & (C_ - 1);
    const float* p0 = E + (size_t)(2 * bz) * CC_ + (size_t)c * C_;
    const int tid = threadIdx.x;

    float v0 = p0[tid] + p0[CC_ + tid];
    float v1 = p0[tid + 256] + p0[CC_ + tid + 256];
    float m = fmaxf(v0, v1);
    #pragma unroll
    for (int off = 32; off > 0; off >>= 1)
        m = fmaxf(m, __shfl_down(m, off, 64));

    __shared__ float sm[4];
    if ((tid & 63) == 0) sm[tid >> 6] = m;
    __syncthreads();
    float M = fmaxf(fmaxf(sm[0], sm[1]), fmaxf(sm[2], sm[3]));

    float e0 = expf(v0 - M), e1 = expf(v1 - M);
    float s = e0 + e1;
    #pragma unroll
    for (int off = 32; off > 0; off >>= 1)
        s += __shfl_down(s, off, 64);

    __shared__ float ss[4];
    if ((tid & 63) == 0) ss[tid >> 6] = s;
    __syncthreads();
    float inv = 1.0f / (ss[0] + ss[1] + ss[2] + ss[3]);

    float a0 = e0 * inv, a1 = e1 * inv;
    size_t o = (size_t)row * C_ + tid;
    unsigned short h0 = f2b(a0);
    Ahi[o] = h0;  Alo[o] = f2b(a0 - b2f(h0));
    unsigned short h1 = f2b(a1);
    Ahi[o + 256] = h1;  Alo[o + 256] = f2b(a1 - b2f(h1));
}

extern "C" void kernel_launch(void* const* d_in, const int* in_sizes, int n_in,
                              void* d_out, int out_size, void* d_ws, size_t ws_size,
                              hipStream_t stream) {
    const float* x  = (const float*)d_in[0];
    const float* gq = (const float*)d_in[1];
    const float* gk = (const float*)d_in[2];
    const float* gv = (const float*)d_in[3];
    const float* Wq = (const float*)d_in[4];
    const float* bq = (const float*)d_in[5];
    const float* Wk = (const float*)d_in[6];
    const float* bk = (const float*)d_in[7];
    const float* Wv = (const float*)d_in[8];
    const float* bv = (const float*)d_in[9];
    float* out = (float*)d_out;

    // Workspace: W planes (batch-independent) + per-batch region.
    const size_t wBytes = 6 * CC_ * 2;                                  // 3 MB
    const size_t perBatch = 2 * TC_ * 2 + TC_ * 4 + 6 * TC_ * 2
                          + 2 * CC_ * 4 + 2 * CC_ * 2;                   // 13 MB
    int bc = 1;
    for (int cand = B_; cand >= 1; cand >>= 1)
        if (wBytes + (size_t)cand * perBatch <= ws_size) { bc = cand; break; }

    char* p = (char*)d_ws;
    auto take = [&](size_t bytes) { char* r = p; p += bytes; return r; };
    unsigned short* Wqh = (unsigned short*)take(CC_ * 2);
    unsigned short* Wql = (unsigned short*)take(CC_ * 2);
    unsigned short* Wkh = (unsigned short*)take(CC_ * 2);
    unsigned short* Wkl = (unsigned short*)take(CC_ * 2);
    unsigned short* Wvh = (unsigned short*)take(CC_ * 2);
    unsigned short* Wvl = (unsigned short*)take(CC_ * 2);
    unsigned short* xThi = (unsigned short*)take((size_t)bc * TC_ * 2);
    unsigned short* xTlo = (unsigned short*)take((size_t)bc * TC_ * 2);
    float*          gvT  = (float*)take((size_t)bc * TC_ * 4);
    unsigned short* Qh = (unsigned short*)take((size_t)bc * TC_ * 2);
    unsigned short* Ql = (unsigned short*)take((size_t)bc * TC_ * 2);
    unsigned short* Kh = (unsigned short*)take((size_t)bc * TC_ * 2);
    unsigned short* Kl = (unsigned short*)take((size_t)bc * TC_ * 2);
    unsigned short* Vh = (unsigned short*)take((size_t)bc * TC_ * 2);
    unsigned short* Vl = (unsigned short*)take((size_t)bc * TC_ * 2);
    float*          E  = (float*)take((size_t)bc * 2 * CC_ * 4);
    unsigned short* Ah = (unsigned short*)take((size_t)bc * CC_ * 2);
    unsigned short* Al = (unsigned short*)take((size_t)bc * CC_ * 2);

    dim3 blk(256);
    split_mat<<<(int)(CC_ / 256), blk, 0, stream>>>(Wq, Wqh, Wql, (int)CC_);
    split_mat<<<(int)(CC_ / 256), blk, 0, stream>>>(Wk, Wkh, Wkl, (int)CC_);
    split_mat<<<(int)(CC_ / 256), blk, 0, stream>>>(Wv, Wvh, Wvl, (int)CC_);

    for (int b_off = 0; b_off < B_; b_off += bc) {
        transpose_split<<<dim3(T_ / 64, C_ / 64, 2 * bc), blk, 0, stream>>>(
            x, gv, xThi, xTlo, gvT, bc, b_off);

        // qT[d,t], kT[d,t]: M=512(d), N=1024(t), K=512(c), GX=8
        gemm_nt<512, 1024, 512, 512, 8, 0><<<dim3(32 * bc), blk, 0, stream>>>(
            Wqh, Wql, 0, xThi, xTlo, TC_, nullptr, 0, Qh, Ql, TC_,
            gq + (size_t)b_off * TC_, TC_, bq, bc);
        gemm_nt<512, 1024, 512, 512, 8, 0><<<dim3(32 * bc), blk, 0, stream>>>(
            Wkh, Wkl, 0, xThi, xTlo, TC_, nullptr, 0, Kh, Kl, TC_,
            gk + (size_t)b_off * TC_, TC_, bk, bc);
        // v[t,d]: M=1024(t), N=512(d), K=512(c), GX=4; gate gvT local-batch
        gemm_nt<1024, 512, 512, 512, 4, 1><<<dim3(32 * bc), blk, 0, stream>>>(
            xThi, xTlo, TC_, Wvh, Wvl, 0, nullptr, 0, Vh, Vl, TC_,
            gvT, TC_, bv, bc);
        // E[c,d]: M=512, N=512, K split 2x512 over t (LD=1024), GX=4
        gemm_nt<512, 512, 512, 1024, 4, 2><<<dim3(16 * 2 * bc), blk, 0, stream>>>(
            Qh, Ql, TC_, Kh, Kl, TC_, E, CC_, nullptr, nullptr, 0, nullptr, 0, nullptr, bc);
        softmax_split<<<dim3(bc * C_), blk, 0, stream>>>(E, Ah, Al);
        // out[c,t]: M=512(c), N=1024(t), K=512(d), GX=8
        gemm_nt<512, 1024, 512, 512, 8, 3><<<dim3(32 * bc), blk, 0, stream>>>(
            Ah, Al, CC_, Vh, Vl, TC_, out + (size_t)b_off * TC_, TC_,
            nullptr, nullptr, 0, nullptr, 0, nullptr, bc);
    }
}